// Round 1
// baseline (11.083 us; speedup 1.0000x reference)
//
#include <hip/hip_runtime.h>

#define BB 8
#define DD 65536
#define GG 1024
#define OUTN 4096

// ---------------- Kernel A: per-block partial dot products ----------------
__global__ __launch_bounds__(256) void ril_partials(
    const float* __restrict__ x,        // (8, 65536)
    const float* __restrict__ weights,  // (1024*65536,)
    const float* __restrict__ min_vals, // (1024,)
    const float* __restrict__ max_vals, // (1024,)
    const int* __restrict__ start_pos,  // (1024,)
    const int* __restrict__ offsets,    // (1024,)
    const int* __restrict__ sizes,      // (1024,)
    float* __restrict__ partials,       // (256,)
    int wlen)
{
    __shared__ float s_min[GG];
    __shared__ float s_max[GG];
    __shared__ int   s_start[GG];
    __shared__ int   s_off[GG];
    __shared__ int   s_size[GG];

    const int t = threadIdx.x;
    for (int i = t; i < GG; i += 256) {
        s_min[i]   = min_vals[i];
        s_max[i]   = max_vals[i];
        s_start[i] = start_pos[i];
        s_off[i]   = offsets[i];
        s_size[i]  = sizes[i];
    }
    __syncthreads();

    const int d = blockIdx.x * 256 + t;   // 256 blocks * 256 thr == 65536 == DD

    // v = mean over the 8 rows (coalesced across threads: consecutive d)
    float v = 0.0f;
#pragma unroll
    for (int b = 0; b < BB; ++b) v += x[b * DD + d];
    v *= (1.0f / BB);

    // g = searchsorted(min_vals, v, side='right') - 1
    //   lo ends as the count of elements <= v
    int lo = 0, hi = GG;
#pragma unroll
    while (lo < hi) {
        int mid = (lo + hi) >> 1;
        if (s_min[mid] <= v) lo = mid + 1; else hi = mid;
    }
    const int g  = lo - 1;
    const int gc = min(max(g, 0), GG - 1);

    const bool in_range = (g >= 0) && (v >= s_min[gc]) && (v <= s_max[gc]);
    const int  pos      = d - s_start[gc];
    const bool valid    = in_range && (pos >= 0) && (pos < s_size[gc]);

    int widx = s_off[gc] + pos;               // offsets fit in int32 (max ~6.7e7)
    widx = min(max(widx, 0), wlen - 1);
    const float w = valid ? weights[widx] : 0.0f;

    float p = v * w;

    // wave64 shuffle reduce (fixed order -> deterministic)
#pragma unroll
    for (int off = 32; off > 0; off >>= 1) p += __shfl_down(p, off);

    __shared__ float s_wsum[4];
    if ((t & 63) == 0) s_wsum[t >> 6] = p;
    __syncthreads();
    if (t == 0) partials[blockIdx.x] = (s_wsum[0] + s_wsum[1]) + (s_wsum[2] + s_wsum[3]);
}

// ---------------- Kernel B: reduce partials, write output ----------------
__global__ __launch_bounds__(256) void ril_finalize(
    const float* __restrict__ partials, // (256,)
    const int* __restrict__ out_mask,   // (4096,) bool pushed as int32
    float* __restrict__ out)            // (8*4096,)
{
    const int t = threadIdx.x;

    float p = partials[t];
#pragma unroll
    for (int off = 32; off > 0; off >>= 1) p += __shfl_down(p, off);

    __shared__ float s_wsum[4];
    __shared__ float s_total;
    if ((t & 63) == 0) s_wsum[t >> 6] = p;
    __syncthreads();
    if (t == 0) s_total = (s_wsum[0] + s_wsum[1]) + (s_wsum[2] + s_wsum[3]);
    __syncthreads();
    const float s = s_total;

    const int i = blockIdx.x * 256 + t;  // 128 blocks cover 32768 outputs
    float val = 0.0f;
    if (i < OUTN && out_mask[i] != 0) val = s;
    out[i] = val;
}

extern "C" void kernel_launch(void* const* d_in, const int* in_sizes, int n_in,
                              void* d_out, int out_size, void* d_ws, size_t ws_size,
                              hipStream_t stream) {
    const float* x        = (const float*)d_in[0];
    const float* weights  = (const float*)d_in[1];
    const float* min_vals = (const float*)d_in[2];
    const float* max_vals = (const float*)d_in[3];
    const int*   start_p  = (const int*)d_in[4];
    const int*   offsets  = (const int*)d_in[5];
    const int*   sizes    = (const int*)d_in[6];
    const int*   out_mask = (const int*)d_in[7];
    float* out = (float*)d_out;
    float* partials = (float*)d_ws;   // 256 floats; every slot written each call

    const int wlen = in_sizes[1];

    ril_partials<<<DD / 256, 256, 0, stream>>>(
        x, weights, min_vals, max_vals, start_p, offsets, sizes, partials, wlen);

    ril_finalize<<<(BB * OUTN) / 256, 256, 0, stream>>>(partials, out_mask, out);
}